// Round 5
// baseline (9.699 us; speedup 1.0000x reference)
//
#include <hip/hip_runtime.h>
#include <cfloat>

// CRPS loss: forecasts (N, P), observation (P), out (P)
// out[p] = mean_j |x_j - y| - (1-eps) * sum_{j,k} |x_j - x_k| / (2 n (n-1))
// with x = max(forecast, CLIP_VALUE).
//
// Sorted form of the pairwise term (exact identity):
//   tri = sum_{j<k} |x_j - x_k| = sum_i (2i - (n-1)) * x_sorted[i]
//   sum_{j,k} = 2 * tri  ->  term2 = tri / (n (n-1))
//
// Sort via Batcher odd-even merge network for n=64, PRUNED to n=50:
// conceptual pads x[50..63] = FLT_MAX never move (every CE sends max to the
// higher index), so every CE with high index >= 50 is an identity op and is
// deleted at source level (compiler can't fold it: IEEE fminf NaN semantics).
// ~410 CEs remain (~820 min/max), all register-static indices.

constexpr int N = 50;
constexpr int NP = 64;            // conceptual padded size (power of 2)
constexpr int BLOCK = 64;
constexpr float CLIP_VALUE = -0.26787253f;
constexpr float EPSILON = 1e-4f;

__global__ __launch_bounds__(BLOCK) void crps_kernel(
    const float* __restrict__ forecasts,    // (N, P)
    const float* __restrict__ observation,  // (P)
    float* __restrict__ out,                // (P)
    int P)
{
    const int p = blockIdx.x * BLOCK + threadIdx.x;
    if (p >= P) return;

    const float y = observation[p];

    float x[N];

    // Load + clip (coalesced per member); term1 on unsorted values.
    float t1a = 0.0f, t1b = 0.0f;
    #pragma unroll
    for (int m = 0; m < N; ++m) {
        const float v = fmaxf(forecasts[m * P + p], CLIP_VALUE);
        x[m] = v;
        if (m & 1) t1b += fabsf(v - y);
        else       t1a += fabsf(v - y);
    }

    // Batcher odd-even mergesort (n=64 network, pruned to indices < 50),
    // ascending.
    #pragma unroll
    for (int pp = 1; pp < NP; pp <<= 1) {
        #pragma unroll
        for (int k = pp; k >= 1; k >>= 1) {
            #pragma unroll
            for (int j = k & (pp - 1); j + k < NP; j += 2 * k) {
                #pragma unroll
                for (int i = 0; i < k; ++i) {
                    if ((i + j + k) < N &&
                        (i + j) / (2 * pp) == (i + j + k) / (2 * pp)) {
                        const float a = x[i + j];
                        const float b = x[i + j + k];
                        x[i + j]     = fminf(a, b);
                        x[i + j + k] = fmaxf(a, b);
                    }
                }
            }
        }
    }

    // tri = sum_i (2i - 49) * x[i], 4 rotating accumulators
    float sa = 0.f, sb = 0.f, sc = 0.f, sd = 0.f;
    #pragma unroll
    for (int i = 0; i < N; i += 4) {
        sa = fmaf((float)(2 * i     - 49), x[i],     sa);
        if (i + 1 < N) sb = fmaf((float)(2 * (i+1) - 49), x[i + 1], sb);
        if (i + 2 < N) sc = fmaf((float)(2 * (i+2) - 49), x[i + 2], sc);
        if (i + 3 < N) sd = fmaf((float)(2 * (i+3) - 49), x[i + 3], sd);
    }
    const float tri = (sa + sb) + (sc + sd);

    const float term1 = (t1a + t1b) * (1.0f / (float)N);
    const float term2 = tri * (1.0f / (float)(N * (N - 1)));
    out[p] = term1 - (1.0f - EPSILON) * term2;
}

extern "C" void kernel_launch(void* const* d_in, const int* in_sizes, int n_in,
                              void* d_out, int out_size, void* d_ws, size_t ws_size,
                              hipStream_t stream) {
    const float* forecasts   = (const float*)d_in[0];  // (50, 64, 336)
    const float* observation = (const float*)d_in[1];  // (64, 336)
    float* out = (float*)d_out;                        // (64, 336)

    const int P = out_size;  // 21504
    const int grid = (P + BLOCK - 1) / BLOCK;

    crps_kernel<<<grid, BLOCK, 0, stream>>>(forecasts, observation, out, P);
}